// Round 5
// baseline (276.947 us; speedup 1.0000x reference)
//
#include <hip/hip_runtime.h>
#include <math.h>

// Problem constants
#define BB   4
#define CC   128
#define HH   64
#define WW   64
#define OUTC 128
#define KK   25     // 5x5 attention taps
#define WLDSF 38400 // 128 c * 25 taps * 12 padded dwords

typedef __attribute__((ext_vector_type(8))) short short8;   // 8 bf16
typedef __attribute__((ext_vector_type(4))) float floatx4;  // MFMA acc

__device__ __forceinline__ unsigned short f32_to_bf16(float v) {
    unsigned int u = __float_as_uint(v);
    u += 0x7fffu + ((u >> 16) & 1u);          // RNE
    return (unsigned short)(u >> 16);
}

// ---------------------------------------------------------------------------
// Kernel 0 (prep):
//  i < 16384:  w2o[o][c] = bf16( sum_r w2[o, c*4+r] )        (o-major)
//  else:       w1tp[c][kk][12] = w1[kk][c][0..8] (pad 9..11): 16B-aligned
//              taps so LDS reads are 2x ds_read_b128 + 1x b32.
// ---------------------------------------------------------------------------
__global__ void prep_kernel(const float* __restrict__ w2,
                            const float* __restrict__ w1,
                            unsigned short* __restrict__ w2o,
                            float* __restrict__ w1tp) {
    int i = blockIdx.x * 256 + threadIdx.x;
    if (i < 16384) {
        int o = i >> 7, c = i & 127;
        const float* p = w2 + o * (4 * CC) + c * 4;
        w2o[o * CC + c] = f32_to_bf16(p[0] + p[1] + p[2] + p[3]);
    } else if (i < 16384 + 38400) {
        int j   = i - 16384;
        int c   = j / 300;
        int rem = j - c * 300;
        int kk  = rem / 12;
        int jj  = rem - kk * 12;
        w1tp[j] = (jj < 9) ? w1[((size_t)kk * CC + c) * 9 + jj] : 0.f;
    }
}

// ---------------------------------------------------------------------------
// Fused kernel: conv1 (3x3) + softmax + local attention + MFMA + 2x2 store.
// grid 256 = (b, h): one full 64-px row per block, 1024 threads (16 waves),
// 1 block/CU (LDS-bound). Round 2-4 lesson: per-lane private weight streams
// cost ~64 us of L1 return bandwidth (16 waves x 600 VMEM x 1KB per CU).
// Here weights are staged in LDS ONCE per block and read WAVE-UNIFORM
// (broadcast: 16B per ds_read_b128, not 1KB) -> weight traffic per CU
// drops ~60x. LDS: weights 153.6KB + pk 6.4KB = 160.0KB; sKT (17.4KB)
// overlays the dead weight region after the conv barrier.
//  conv1 : lane = px (full row), wave = 8-channel slice. 9 coalesced x
//          loads per channel feed 225 FMA; weights broadcast from LDS.
//          Merge: 25 conflict-free ds-atomics per wave (64 distinct px).
//  softmax: in-register per phase-C thread (redundant, zero barriers).
//  phase C: x windows straight from L1/L2 (rows warm from conv).
//  MFMA  : C[128 o][64 px]: 16 waves = 8(o-tile) x 2(px-half).
// ---------------------------------------------------------------------------
__global__ __launch_bounds__(1024, 4) void fused_kernel(
        const float* __restrict__ x,
        const float* __restrict__ w1tp,
        const unsigned short* __restrict__ w2o,
        const float* __restrict__ b1,
        const float* __restrict__ b2,
        float* __restrict__ out) {
    __shared__ float wlds[WLDSF];               // 153.6 KB (sKT overlays)
    __shared__ float pk[KK * 64];               // logits (6.4 KB)
    unsigned short* sKT = (unsigned short*)wlds; // 64 x 136 bf16 (17.4 KB)

    // XCD swizzle (256 % 8 == 0 -> bijective): 32 consecutive (b,h) per
    // XCD -> neighboring rows (shared x lines h+-2) on the same L2.
    int bid0 = blockIdx.x;
    int bid  = (bid0 & 7) * 32 + (bid0 >> 3);
    int h = bid & 63;
    int b = bid >> 6;
    int t = threadIdx.x;
    int lane = t & 63;

    // ---- stage weights to LDS + init logits with bias ----
    {
        const float4* src = (const float4*)w1tp;
        float4* dst = (float4*)wlds;
        for (int i = t; i < WLDSF / 4; i += 1024) dst[i] = src[i];
        for (int i = t; i < KK * 64; i += 1024) pk[i] = b1[i >> 6];
    }
    __syncthreads();

    // ---- conv1 3x3 SAME: lane = px, wave = 8 channels ----
    int px = lane;
    int wv = t >> 6;                 // 0..15
    float mt = (h > 0) ? 1.f : 0.f, mb = (h < HH - 1) ? 1.f : 0.f;
    float ml = (px > 0) ? 1.f : 0.f, mr = (px < WW - 1) ? 1.f : 0.f;
    int ya = (h > 0) ? h - 1 : 0;
    int yb = (h < HH - 1) ? h + 1 : HH - 1;
    int xl = (px > 0) ? px - 1 : 0;
    int xr = (px < WW - 1) ? px + 1 : WW - 1;

    float acc[KK];
    #pragma unroll
    for (int k = 0; k < KK; ++k) acc[k] = 0.f;

    const float* xb = x + (size_t)b * CC * (HH * WW);
    #pragma unroll 2
    for (int ci = 0; ci < 8; ++ci) {
        int c = wv * 8 + ci;
        const float* xp = xb + (size_t)c * (HH * WW);
        const float* r0 = xp + ya * WW;
        const float* r1 = xp + h  * WW;
        const float* r2 = xp + yb * WW;
        float x00 = r0[xl] * (mt * ml), x01 = r0[px] * mt, x02 = r0[xr] * (mt * mr);
        float x10 = r1[xl] * ml,        x11 = r1[px],      x12 = r1[xr] * mr;
        float x20 = r2[xl] * (mb * ml), x21 = r2[px] * mb, x22 = r2[xr] * (mb * mr);

        const float* wc = wlds + c * 300;        // wave-uniform -> broadcast
        #pragma unroll
        for (int kk = 0; kk < KK; ++kk) {
            float4 wA = *(const float4*)(wc + kk * 12);
            float4 wB = *(const float4*)(wc + kk * 12 + 4);
            float  w8 = wc[kk * 12 + 8];
            acc[kk] += x00 * wA.x + x01 * wA.y + x02 * wA.z
                     + x10 * wA.w + x11 * wB.x + x12 * wB.y
                     + x20 * wB.z + x21 * wB.w + x22 * w8;
        }
    }
    // merge 16 wave-partials (64 distinct px per wave -> conflict-free)
    #pragma unroll
    for (int k = 0; k < KK; ++k)
        atomicAdd(&pk[k * 64 + px], acc[k]);
    __syncthreads();   // conv done: weights dead, sKT region reusable

    // ---- phase C: in-register softmax + attention straight from L1/L2 ----
    // thread = (pp2 = t&31 -> px {2pp2, 2pp2+1}, cw = t>>5 -> 4 channels)
    int pp2 = t & 31, cw = t >> 5;

    float2 lg[KK];
    #pragma unroll
    for (int k = 0; k < KK; ++k) lg[k] = *(const float2*)&pk[k * 64 + 2 * pp2];
    float m0 = -1e30f, m1 = -1e30f;
    #pragma unroll
    for (int k = 0; k < KK; ++k) { m0 = fmaxf(m0, lg[k].x); m1 = fmaxf(m1, lg[k].y); }
    float s0 = 0.f, s1 = 0.f;
    #pragma unroll
    for (int k = 0; k < KK; ++k) {
        lg[k].x = __expf(lg[k].x - m0); s0 += lg[k].x;
        lg[k].y = __expf(lg[k].y - m1); s1 += lg[k].y;
    }
    float i0 = 1.f / s0, i1 = 1.f / s1;
    #pragma unroll
    for (int k = 0; k < KK; ++k) { lg[k].x *= i0; lg[k].y *= i1; }

    // window geometry: 5 rows x 3 float2 loads (even col offsets -> a
    // float2 is fully in-bounds or fully out -> single mask per pair)
    int colg = 2 * pp2 - 2;
    int coff[3]; float cmask[3];
    #pragma unroll
    for (int j = 0; j < 3; ++j) {
        int cg = colg + 2 * j;
        cmask[j] = (cg >= 0 && cg <= WW - 2) ? 1.f : 0.f;
        coff[j]  = min(max(cg, 0), WW - 2);
    }
    int yoff[5]; float msk[15];
    #pragma unroll
    for (int di = 0; di < 5; ++di) {
        int y = h + di - 2;
        float rm = (y >= 0 && y < HH) ? 1.f : 0.f;
        yoff[di] = min(max(y, 0), HH - 1) * WW;
        #pragma unroll
        for (int j = 0; j < 3; ++j) msk[di * 3 + j] = rm * cmask[j];
    }

    #pragma unroll 2
    for (int i4 = 0; i4 < 4; ++i4) {
        int c = i4 * 32 + cw;
        const float* xc = xb + (size_t)c * (HH * WW);
        float2 xv[15];
        #pragma unroll
        for (int di = 0; di < 5; ++di)
            #pragma unroll
            for (int j = 0; j < 3; ++j) {
                float2 v = *(const float2*)(xc + yoff[di] + coff[j]);
                float mm = msk[di * 3 + j];
                xv[di * 3 + j] = make_float2(v.x * mm, v.y * mm);
            }
        float t0 = 0.f, t1 = 0.f;
        #pragma unroll
        for (int di = 0; di < 5; ++di) {
            float2 x01 = xv[di * 3 + 0];
            float2 x23 = xv[di * 3 + 1];
            float2 x45 = xv[di * 3 + 2];
            t0 += lg[di*5+0].x * x01.x + lg[di*5+1].x * x01.y
                + lg[di*5+2].x * x23.x + lg[di*5+3].x * x23.y
                + lg[di*5+4].x * x45.x;
            t1 += lg[di*5+0].y * x01.y + lg[di*5+1].y * x23.x
                + lg[di*5+2].y * x23.y + lg[di*5+3].y * x45.x
                + lg[di*5+4].y * x45.y;
        }
        sKT[(2 * pp2) * 136 + c]     = f32_to_bf16(t0);
        sKT[(2 * pp2 + 1) * 136 + c] = f32_to_bf16(t1);
    }
    __syncthreads();

    // ---- MFMA: C[o][px] = sum_c W2s[o][c] * s[c][px] ----
    // wave = (ot = wv&7 -> o rows [16ot,16ot+16), ph = wv>>3 -> px half)
    int ot = wv & 7, ph = wv >> 3;
    int fpx = lane & 15, quad = lane >> 4;
    floatx4 am[2] = {{0.f,0.f,0.f,0.f},{0.f,0.f,0.f,0.f}};
    #pragma unroll
    for (int ks = 0; ks < 4; ++ks) {
        short8 bf0 = *(const short8*)&sKT[(32*ph      + fpx) * 136 + ks*32 + quad*8];
        short8 bf1 = *(const short8*)&sKT[(32*ph + 16 + fpx) * 136 + ks*32 + quad*8];
        short8 af  = *(const short8*)&w2o[(size_t)(16*ot + fpx) * CC + ks*32 + quad*8];
        am[0] = __builtin_amdgcn_mfma_f32_16x16x32_bf16(af, bf0, am[0], 0, 0, 0);
        am[1] = __builtin_amdgcn_mfma_f32_16x16x32_bf16(af, bf1, am[1], 0, 0, 0);
    }

    // ---- epilogue: D[row=quad*4+reg][col=fpx] + b2, 2x2-replicated write ----
    float* ob = out + (size_t)b * OUTC * (4 * HH * WW);
    int y0 = 2 * h;
    #pragma unroll
    for (int nt = 0; nt < 2; ++nt) {
        #pragma unroll
        for (int reg = 0; reg < 4; ++reg) {
            int o   = 16*ot + quad*4 + reg;
            int pxo = 32*ph + 16*nt + fpx;
            float v = am[nt][reg] + b2[o];
            float2 v2 = make_float2(v, v);
            float* r0p = ob + ((size_t)o * (2*HH) + y0) * (2*WW) + 2*pxo;
            *(float2*)(r0p)        = v2;
            *(float2*)(r0p + 2*WW) = v2;
        }
    }
}

// ---------------------------------------------------------------------------
extern "C" void kernel_launch(void* const* d_in, const int* in_sizes, int n_in,
                              void* d_out, int out_size, void* d_ws, size_t ws_size,
                              hipStream_t stream) {
    const float* x  = (const float*)d_in[0];
    const float* w1 = (const float*)d_in[1];
    const float* b1 = (const float*)d_in[2];
    const float* w2 = (const float*)d_in[3];
    const float* b2 = (const float*)d_in[4];
    float* out = (float*)d_out;

    unsigned short* w2o = (unsigned short*)d_ws;               // 32 KB
    float* w1tp = (float*)(w2o + (size_t)OUTC * CC);           // 153.6 KB

    prep_kernel<<<(16384 + 38400 + 255) / 256, 256, 0, stream>>>(w2, w1, w2o, w1tp);
    fused_kernel<<<BB * HH, 1024, 0, stream>>>(x, w1tp, w2o, b1, b2, out);
}